// Round 5
// baseline (4926.126 us; speedup 1.0000x reference)
//
#include <hip/hip_runtime.h>
#include <math.h>

typedef float f32x4 __attribute__((ext_vector_type(4)));

#define NB 768              // blocks; block p owns chunk j=p&63 of plane c=p>>6
#define BS 256              // threads per block
#define NBATCH 64
#define NCH 12
#define NQ 4
#define PLANE 65536         // floats per (b,c) plane
#define PLANE4 16384        // f32x4 per plane
#define BATCH4 196608       // f32x4 per batch (12 planes)
#define CHUNK4 256          // f32x4 per block per batch (1 per thread)

#define LOAD_A(p)  __hip_atomic_load((p),  __ATOMIC_RELAXED, __HIP_MEMORY_SCOPE_AGENT)
#define STORE_A(p,v) __hip_atomic_store((p), (v), __ATOMIC_RELAXED, __HIP_MEMORY_SCOPE_AGENT)

// ---------------- VQC gate helpers (all indices compile-time) ----------------
__device__ __forceinline__ void apply_rz(float* sr, float* si, int mask, float theta) {
    float c, s;
    __sincosf(0.5f * theta, &s, &c);
    #pragma unroll
    for (int i = 0; i < 16; ++i) {
        float r = sr[i], im = si[i];
        if (i & mask) { sr[i] = r * c - im * s; si[i] = im * c + r * s; }
        else          { sr[i] = r * c + im * s; si[i] = im * c - r * s; }
    }
}

__device__ __forceinline__ void apply_ry(float* sr, float* si, int mask, float theta) {
    float c, s;
    __sincosf(0.5f * theta, &s, &c);
    #pragma unroll
    for (int i = 0; i < 16; ++i) {
        if (i & mask) continue;
        int jj = i | mask;
        float r0 = sr[i], i0 = si[i], r1 = sr[jj], i1 = si[jj];
        sr[i]  = c * r0 - s * r1;  si[i]  = c * i0 - s * i1;
        sr[jj] = s * r0 + c * r1;  si[jj] = s * i0 + c * i1;
    }
}

__device__ __forceinline__ void apply_cnot(float* sr, float* si, int mc, int mt) {
    #pragma unroll
    for (int i = 0; i < 16; ++i) {
        if ((i & mc) && !(i & mt)) {
            int jj = i | mt;
            float tr = sr[i], ti = si[i];
            sr[i] = sr[jj]; si[i] = si[jj];
            sr[jj] = tr;    si[jj] = ti;
        }
    }
}

__device__ __forceinline__ void apply_u3(float* sr, float* si, int mask,
                                         float theta, float phi, float lam) {
    float c = __cosf(0.5f * theta), s = __sinf(0.5f * theta);
    float cl, sl, cp, sp, cpl, spl;
    __sincosf(lam, &sl, &cl);
    __sincosf(phi, &sp, &cp);
    __sincosf(phi + lam, &spl, &cpl);
    float u01r = -cl * s, u01i = -sl * s;
    float u10r =  cp * s, u10i =  sp * s;
    float u11r =  cpl * c, u11i = spl * c;
    #pragma unroll
    for (int i = 0; i < 16; ++i) {
        if (i & mask) continue;
        int jj = i | mask;
        float r0 = sr[i], i0 = si[i], r1 = sr[jj], i1 = si[jj];
        sr[i]  = c * r0 + (u01r * r1 - u01i * i1);
        si[i]  = c * i0 + (u01r * i1 + u01i * r1);
        sr[jj] = (u10r * r0 - u10i * i0) + (u11r * r1 - u11i * i1);
        si[jj] = (u10r * i0 + u10i * r0) + (u11r * i1 + u11i * r1);
    }
}

// ---------------- Fused single-pass kernel (regular launch, 768 blocks all resident) ----------------
// flags layout: cntA[64*12] | cntB[64] | ready[64]  (zeroed before launch)
__global__ __launch_bounds__(BS, 4) void fused_kernel(
        const float* __restrict__ x, const float* __restrict__ w,
        const float* __restrict__ fcw, const float* __restrict__ fcb,
        float* __restrict__ out, int* __restrict__ flags,
        float* __restrict__ part, float* __restrict__ att)
{
    int* cntA  = flags;          // [64][12], target 64 per plane
    int* cntB  = flags + 768;    // [64], target 12 per batch
    int* ready = flags + 832;    // [64]

    const int p = blockIdx.x, t = threadIdx.x;
    const int c = p >> 6, j = p & 63;    // plane channel, chunk-within-plane
    const int lane = t & 63, wid = t >> 6;
    __shared__ float wsum[2][4];

    const f32x4* xv = reinterpret_cast<const f32x4*>(x);
    f32x4* ov = reinterpret_cast<f32x4*>(out);
    const size_t base = (size_t)c * PLANE4 + (size_t)j * CHUNK4 + t;

    auto wave_sum = [&](float v) {
        #pragma unroll
        for (int off = 32; off; off >>= 1) v += __shfl_xor(v, off);
        return v;   // full sum on all 64 lanes
    };

    // last-arriver's wave 0: reduce 768 partials -> 12 means -> VQC -> att -> ready
    auto service = [&](int b) {
        __threadfence();   // acquire: order after the counter chain before reading part
        float m[NCH];
        #pragma unroll
        for (int cc = 0; cc < NCH; ++cc) {
            float v = LOAD_A(&part[(size_t)b * 768 + cc * 64 + lane]);
            m[cc] = wave_sum(v) * (1.0f / (float)PLANE);
        }
        float sr[16], si[16];
        #pragma unroll
        for (int i = 0; i < 16; ++i) { sr[i] = 0.25f; si[i] = 0.f; }
        #pragma unroll
        for (int q = 0; q < NQ; ++q) {
            const int mask = 1 << (3 - q);
            apply_rz(sr, si, mask, m[q * 3 + 0]);
            apply_ry(sr, si, mask, m[q * 3 + 1]);
            apply_rz(sr, si, mask, m[q * 3 + 2]);
        }
        apply_cnot(sr, si, 1 << 3, 1 << 2);
        apply_cnot(sr, si, 1 << 2, 1 << 1);
        apply_cnot(sr, si, 1 << 1, 1 << 0);
        apply_cnot(sr, si, 1 << 0, 1 << 3);
        #pragma unroll
        for (int q = 0; q < NQ; ++q) {
            const int mask = 1 << (3 - q);
            apply_u3(sr, si, mask, w[q * 3 + 0], w[q * 3 + 1], w[q * 3 + 2]);
        }
        float z[NQ];
        #pragma unroll
        for (int q = 0; q < NQ; ++q) {
            const int mask = 1 << (3 - q);
            float acc = 0.f;
            #pragma unroll
            for (int i = 0; i < 16; ++i) {
                float pr = sr[i] * sr[i] + si[i] * si[i];
                acc += (i & mask) ? -pr : pr;
            }
            z[q] = acc;
        }
        if (lane < NCH) {
            float a = fcb[lane];
            #pragma unroll
            for (int q = 0; q < NQ; ++q) a += z[q] * fcw[lane * NQ + q];
            STORE_A(&att[b * NCH + lane], 1.0f / (1.0f + expf(-a)));
        }
        __threadfence();   // release: att visible before ready
        if (lane == 0)
            __hip_atomic_store(&ready[b], 1, __ATOMIC_RELEASE, __HIP_MEMORY_SCOPE_AGENT);
    };

    // phase A: load my f32x4 of batch b, block-reduce, flag arrival
    auto phaseA = [&](int b) -> f32x4 {
        f32x4 v = __builtin_nontemporal_load(&xv[(size_t)b * BATCH4 + base]);
        float s = wave_sum((v.x + v.y) + (v.z + v.w));
        if (lane == 0) wsum[b & 1][wid] = s;
        __syncthreads();
        int srv = 0;
        if (t == 0) {
            float cs = (wsum[b & 1][0] + wsum[b & 1][1]) + (wsum[b & 1][2] + wsum[b & 1][3]);
            STORE_A(&part[(size_t)b * 768 + c * 64 + j], cs);
            __threadfence();
            int o = __hip_atomic_fetch_add(&cntA[b * NCH + c], 1,
                                           __ATOMIC_ACQ_REL, __HIP_MEMORY_SCOPE_AGENT);
            if (o == 63) {
                int o2 = __hip_atomic_fetch_add(&cntB[b], 1,
                                                __ATOMIC_ACQ_REL, __HIP_MEMORY_SCOPE_AGENT);
                srv = (o2 == NCH - 1);
            }
        }
        if (wid == 0) {                 // wave-uniform branch; lane0 broadcasts
            srv = __shfl(srv, 0);
            if (srv) service(b);
        }
        return v;
    };

    // phase B: wait for att of batch b, scale held data, stream out
    auto phaseB = [&](int b, f32x4 h) {
        if (t == 0) {
            while (__hip_atomic_load(&ready[b], __ATOMIC_ACQUIRE, __HIP_MEMORY_SCOPE_AGENT) == 0)
                __builtin_amdgcn_s_sleep(2);
        }
        __syncthreads();    // everyone ordered after t0's acquire
        float a = LOAD_A(&att[b * NCH + c]);
        __builtin_nontemporal_store(h * a, &ov[(size_t)b * BATCH4 + base]);
    };

    // DEPTH=4 software pipeline, static hold registers (no runtime indexing)
    f32x4 h0 = phaseA(0), h1 = phaseA(1), h2 = phaseA(2), h3 = phaseA(3);
    for (int bg = 4; bg < NBATCH; bg += 4) {
        f32x4 v;
        v = phaseA(bg + 0); phaseB(bg - 4, h0); h0 = v;
        v = phaseA(bg + 1); phaseB(bg - 3, h1); h1 = v;
        v = phaseA(bg + 2); phaseB(bg - 2, h2); h2 = v;
        v = phaseA(bg + 3); phaseB(bg - 1, h3); h3 = v;
    }
    phaseB(NBATCH - 4, h0); phaseB(NBATCH - 3, h1);
    phaseB(NBATCH - 2, h2); phaseB(NBATCH - 1, h3);
}

extern "C" void kernel_launch(void* const* d_in, const int* in_sizes, int n_in,
                              void* d_out, int out_size, void* d_ws, size_t ws_size,
                              hipStream_t stream) {
    const float* x   = (const float*)d_in[0];
    const float* vw  = (const float*)d_in[1];
    const float* fcw = (const float*)d_in[2];
    const float* fcb = (const float*)d_in[3];
    float* out = (float*)d_out;

    int*   flags = (int*)d_ws;                                   // 896 ints
    float* part  = (float*)((char*)d_ws + 4096);                 // [64][768]
    float* att   = (float*)((char*)d_ws + 4096 + 768 * 64 * 4);  // [64][12]

    hipMemsetAsync(flags, 0, 896 * sizeof(int), stream);         // stateless re-init

    fused_kernel<<<dim3(NB), dim3(BS), 0, stream>>>(x, vw, fcw, fcb,
                                                    out, flags, part, att);
}

// Round 6
// 139.195 us; speedup vs baseline: 35.3901x; 35.3901x over previous
//
#include <hip/hip_runtime.h>
#include <math.h>

typedef float f32x4 __attribute__((ext_vector_type(4)));

#define NB 768              // one block per (b,c) plane
#define BS 256
#define NBATCH 64
#define NCH 12
#define NQ 4
#define PLANE 65536         // floats per plane
#define PLANE4 16384        // f32x4 per plane
#define IT 64               // f32x4 per thread per plane

#define LOAD_A(p)    __hip_atomic_load((p),  __ATOMIC_RELAXED, __HIP_MEMORY_SCOPE_AGENT)
#define STORE_A(p,v) __hip_atomic_store((p), (v), __ATOMIC_RELAXED, __HIP_MEMORY_SCOPE_AGENT)

// ---------------- VQC gate helpers (all indices compile-time) ----------------
__device__ __forceinline__ void apply_rz(float* sr, float* si, int mask, float theta) {
    float c, s;
    __sincosf(0.5f * theta, &s, &c);
    #pragma unroll
    for (int i = 0; i < 16; ++i) {
        float r = sr[i], im = si[i];
        if (i & mask) { sr[i] = r * c - im * s; si[i] = im * c + r * s; }
        else          { sr[i] = r * c + im * s; si[i] = im * c - r * s; }
    }
}

__device__ __forceinline__ void apply_ry(float* sr, float* si, int mask, float theta) {
    float c, s;
    __sincosf(0.5f * theta, &s, &c);
    #pragma unroll
    for (int i = 0; i < 16; ++i) {
        if (i & mask) continue;
        int jj = i | mask;
        float r0 = sr[i], i0 = si[i], r1 = sr[jj], i1 = si[jj];
        sr[i]  = c * r0 - s * r1;  si[i]  = c * i0 - s * i1;
        sr[jj] = s * r0 + c * r1;  si[jj] = s * i0 + c * i1;
    }
}

__device__ __forceinline__ void apply_cnot(float* sr, float* si, int mc, int mt) {
    #pragma unroll
    for (int i = 0; i < 16; ++i) {
        if ((i & mc) && !(i & mt)) {
            int jj = i | mt;
            float tr = sr[i], ti = si[i];
            sr[i] = sr[jj]; si[i] = si[jj];
            sr[jj] = tr;    si[jj] = ti;
        }
    }
}

__device__ __forceinline__ void apply_u3(float* sr, float* si, int mask,
                                         float theta, float phi, float lam) {
    float c = __cosf(0.5f * theta), s = __sinf(0.5f * theta);
    float cl, sl, cp, sp, cpl, spl;
    __sincosf(lam, &sl, &cl);
    __sincosf(phi, &sp, &cp);
    __sincosf(phi + lam, &spl, &cpl);
    float u01r = -cl * s, u01i = -sl * s;
    float u10r =  cp * s, u10i =  sp * s;
    float u11r =  cpl * c, u11i = spl * c;
    #pragma unroll
    for (int i = 0; i < 16; ++i) {
        if (i & mask) continue;
        int jj = i | mask;
        float r0 = sr[i], i0 = si[i], r1 = sr[jj], i1 = si[jj];
        sr[i]  = c * r0 + (u01r * r1 - u01i * i1);
        si[i]  = c * i0 + (u01r * i1 + u01i * r1);
        sr[jj] = (u10r * r0 - u10i * i0) + (u11r * r1 - u11i * i1);
        si[jj] = (u10r * i0 + u10i * r0) + (u11r * i1 + u11i * r1);
    }
}

// ---------------- One-kernel fusion: per-plane mean -> 12-block sync -> VQC -> scale ----
// ws: cnt[64] ints | meanbuf[768] floats. cnt zeroed before each launch.
__global__ __launch_bounds__(BS, 4) void fused_kernel(
        const float* __restrict__ x, const float* __restrict__ w,
        const float* __restrict__ fcw, const float* __restrict__ fcb,
        float* __restrict__ out, int* __restrict__ cnt,
        float* __restrict__ meanbuf)
{
    const int p = blockIdx.x;            // plane index = b*12 + c
    const int b = p / NCH, c = p - b * NCH;
    const int t = threadIdx.x;
    const int lane = t & 63, wid = t >> 6;

    const f32x4* xp = reinterpret_cast<const f32x4*>(x) + (size_t)p * PLANE4;
    f32x4*       op = reinterpret_cast<f32x4*>(out)     + (size_t)p * PLANE4;

    // ---- phase 1: mean of my plane (temporal loads: warm L3 for phase 2) ----
    float s0 = 0.f, s1 = 0.f, s2 = 0.f, s3 = 0.f;
    for (int i = 0; i < IT; i += 4) {
        f32x4 a = xp[t + (i + 0) * BS];
        f32x4 d = xp[t + (i + 1) * BS];
        f32x4 e = xp[t + (i + 2) * BS];
        f32x4 f = xp[t + (i + 3) * BS];
        s0 += (a.x + a.y) + (a.z + a.w);
        s1 += (d.x + d.y) + (d.z + d.w);
        s2 += (e.x + e.y) + (e.z + e.w);
        s3 += (f.x + f.y) + (f.z + f.w);
    }
    float sum = (s0 + s1) + (s2 + s3);
    #pragma unroll
    for (int off = 32; off; off >>= 1) sum += __shfl_xor(sum, off);
    __shared__ float wsum[4];
    if (lane == 0) wsum[wid] = sum;
    __syncthreads();

    // ---- publish mean, sync the 12 blocks of batch b ----
    if (t == 0) {
        float tot = (wsum[0] + wsum[1]) + (wsum[2] + wsum[3]);
        STORE_A(&meanbuf[p], tot * (1.0f / (float)PLANE));
        __hip_atomic_fetch_add(&cnt[b], 1, __ATOMIC_ACQ_REL, __HIP_MEMORY_SCOPE_AGENT);
        while (__hip_atomic_load(&cnt[b], __ATOMIC_ACQUIRE, __HIP_MEMORY_SCOPE_AGENT) < NCH)
            __builtin_amdgcn_s_sleep(1);
    }
    __syncthreads();   // all threads ordered after t0's acquire

    // ---- VQC for batch b (block-uniform, computed redundantly by all threads) ----
    float m[NCH];
    #pragma unroll
    for (int cc = 0; cc < NCH; ++cc) m[cc] = LOAD_A(&meanbuf[b * NCH + cc]);

    float sr[16], si[16];
    #pragma unroll
    for (int i = 0; i < 16; ++i) { sr[i] = 0.25f; si[i] = 0.f; }
    #pragma unroll
    for (int q = 0; q < NQ; ++q) {
        const int mask = 1 << (3 - q);
        apply_rz(sr, si, mask, m[q * 3 + 0]);
        apply_ry(sr, si, mask, m[q * 3 + 1]);
        apply_rz(sr, si, mask, m[q * 3 + 2]);
    }
    apply_cnot(sr, si, 1 << 3, 1 << 2);
    apply_cnot(sr, si, 1 << 2, 1 << 1);
    apply_cnot(sr, si, 1 << 1, 1 << 0);
    apply_cnot(sr, si, 1 << 0, 1 << 3);
    #pragma unroll
    for (int q = 0; q < NQ; ++q) {
        const int mask = 1 << (3 - q);
        apply_u3(sr, si, mask, w[q * 3 + 0], w[q * 3 + 1], w[q * 3 + 2]);
    }
    float z[NQ];
    #pragma unroll
    for (int q = 0; q < NQ; ++q) {
        const int mask = 1 << (3 - q);
        float acc = 0.f;
        #pragma unroll
        for (int i = 0; i < 16; ++i) {
            float pr = sr[i] * sr[i] + si[i] * si[i];
            acc += (i & mask) ? -pr : pr;
        }
        z[q] = acc;
    }
    float a = fcb[c];
    #pragma unroll
    for (int q = 0; q < NQ; ++q) a += z[q] * fcw[c * NQ + q];
    const float att = 1.0f / (1.0f + expf(-a));

    // ---- phase 2: re-read my plane (L3-hot) * att -> NT store ----
    #pragma unroll 4
    for (int i = 0; i < IT; ++i) {
        f32x4 v = xp[t + i * BS];
        __builtin_nontemporal_store(v * att, &op[t + i * BS]);
    }
}

extern "C" void kernel_launch(void* const* d_in, const int* in_sizes, int n_in,
                              void* d_out, int out_size, void* d_ws, size_t ws_size,
                              hipStream_t stream) {
    const float* x   = (const float*)d_in[0];
    const float* vw  = (const float*)d_in[1];
    const float* fcw = (const float*)d_in[2];
    const float* fcb = (const float*)d_in[3];
    float* out = (float*)d_out;

    int*   cnt     = (int*)d_ws;                      // [64]
    float* meanbuf = (float*)((char*)d_ws + 1024);    // [768]

    hipMemsetAsync(cnt, 0, NBATCH * sizeof(int), stream);   // stateless re-init
    fused_kernel<<<dim3(NB), dim3(BS), 0, stream>>>(x, vw, fcw, fcb, out, cnt, meanbuf);
}

// Round 7
// 96.241 us; speedup vs baseline: 51.1852x; 1.4463x over previous
//
#include <hip/hip_runtime.h>
#include <math.h>

typedef float f32x4 __attribute__((ext_vector_type(4)));

#define NSEG 3072           // 4 segments per plane
#define SEG4 4096           // f32x4 per segment
#define NB 768              // one block per (b,c) plane in kernel 2
#define BS 256
#define NCH 12
#define NQ 4
#define PLANE 65536         // floats per plane
#define PLANE4 16384        // f32x4 per plane

// ---------------- VQC gate helpers (all indices compile-time) ----------------
__device__ __forceinline__ void apply_rz(float* sr, float* si, int mask, float theta) {
    float c, s;
    __sincosf(0.5f * theta, &s, &c);
    #pragma unroll
    for (int i = 0; i < 16; ++i) {
        float r = sr[i], im = si[i];
        if (i & mask) { sr[i] = r * c - im * s; si[i] = im * c + r * s; }
        else          { sr[i] = r * c + im * s; si[i] = im * c - r * s; }
    }
}

__device__ __forceinline__ void apply_ry(float* sr, float* si, int mask, float theta) {
    float c, s;
    __sincosf(0.5f * theta, &s, &c);
    #pragma unroll
    for (int i = 0; i < 16; ++i) {
        if (i & mask) continue;
        int jj = i | mask;
        float r0 = sr[i], i0 = si[i], r1 = sr[jj], i1 = si[jj];
        sr[i]  = c * r0 - s * r1;  si[i]  = c * i0 - s * i1;
        sr[jj] = s * r0 + c * r1;  si[jj] = s * i0 + c * i1;
    }
}

__device__ __forceinline__ void apply_cnot(float* sr, float* si, int mc, int mt) {
    #pragma unroll
    for (int i = 0; i < 16; ++i) {
        if ((i & mc) && !(i & mt)) {
            int jj = i | mt;
            float tr = sr[i], ti = si[i];
            sr[i] = sr[jj]; si[i] = si[jj];
            sr[jj] = tr;    si[jj] = ti;
        }
    }
}

__device__ __forceinline__ void apply_u3(float* sr, float* si, int mask,
                                         float theta, float phi, float lam) {
    float c = __cosf(0.5f * theta), s = __sinf(0.5f * theta);
    float cl, sl, cp, sp, cpl, spl;
    __sincosf(lam, &sl, &cl);
    __sincosf(phi, &sp, &cp);
    __sincosf(phi + lam, &spl, &cpl);
    float u01r = -cl * s, u01i = -sl * s;
    float u10r =  cp * s, u10i =  sp * s;
    float u11r =  cpl * c, u11i = spl * c;
    #pragma unroll
    for (int i = 0; i < 16; ++i) {
        if (i & mask) continue;
        int jj = i | mask;
        float r0 = sr[i], i0 = si[i], r1 = sr[jj], i1 = si[jj];
        sr[i]  = c * r0 + (u01r * r1 - u01i * i1);
        si[i]  = c * i0 + (u01r * i1 + u01i * r1);
        sr[jj] = (u10r * r0 - u10i * i0) + (u11r * r1 - u11i * i1);
        si[jj] = (u10r * i0 + u10i * r0) + (u11r * i1 + u11i * r1);
    }
}

// ---------------- Kernel 1: per-segment partial sums (temporal loads warm L3) ----
__global__ __launch_bounds__(256) void mean_partial(const float* __restrict__ x,
                                                    float* __restrict__ part) {
    const int seg = blockIdx.x;
    const f32x4* p = reinterpret_cast<const f32x4*>(x) + (size_t)seg * SEG4;
    const int t = threadIdx.x;
    float s0 = 0.f, s1 = 0.f, s2 = 0.f, s3 = 0.f;
    #pragma unroll
    for (int i = 0; i < 16; i += 4) {
        f32x4 a = p[t + (i + 0) * 256];
        f32x4 b = p[t + (i + 1) * 256];
        f32x4 c = p[t + (i + 2) * 256];
        f32x4 d = p[t + (i + 3) * 256];
        s0 += (a.x + a.y) + (a.z + a.w);
        s1 += (b.x + b.y) + (b.z + b.w);
        s2 += (c.x + c.y) + (c.z + c.w);
        s3 += (d.x + d.y) + (d.z + d.w);
    }
    float sum = (s0 + s1) + (s2 + s3);
    #pragma unroll
    for (int off = 32; off; off >>= 1) sum += __shfl_down(sum, off);
    __shared__ float wsum[4];
    if ((threadIdx.x & 63) == 0) wsum[threadIdx.x >> 6] = sum;
    __syncthreads();
    if (threadIdx.x == 0) part[seg] = (wsum[0] + wsum[1]) + (wsum[2] + wsum[3]);
}

// ---------------- Kernel 2: per-plane VQC (redundant, block-uniform) + scale ----
__global__ __launch_bounds__(256) void scale_vqc(const float* __restrict__ x,
                                                 const float* __restrict__ part,
                                                 const float* __restrict__ w,
                                                 const float* __restrict__ fcw,
                                                 const float* __restrict__ fcb,
                                                 float* __restrict__ out) {
    const int p = blockIdx.x;            // plane = b*12 + c
    const int b = p / NCH, c = p - b * NCH;

    // 12 channel means of batch b from the 48 partials (block-uniform)
    float m[NCH];
    #pragma unroll
    for (int cc = 0; cc < NCH; ++cc) {
        const float* q = &part[(size_t)(b * NCH + cc) * 4];
        m[cc] = ((q[0] + q[1]) + (q[2] + q[3])) * (1.0f / (float)PLANE);
    }

    // VQC (every thread redundantly; ~1600 VALU ops, hidden under load issue)
    float sr[16], si[16];
    #pragma unroll
    for (int i = 0; i < 16; ++i) { sr[i] = 0.25f; si[i] = 0.f; }
    #pragma unroll
    for (int q = 0; q < NQ; ++q) {
        const int mask = 1 << (3 - q);
        apply_rz(sr, si, mask, m[q * 3 + 0]);
        apply_ry(sr, si, mask, m[q * 3 + 1]);
        apply_rz(sr, si, mask, m[q * 3 + 2]);
    }
    apply_cnot(sr, si, 1 << 3, 1 << 2);
    apply_cnot(sr, si, 1 << 2, 1 << 1);
    apply_cnot(sr, si, 1 << 1, 1 << 0);
    apply_cnot(sr, si, 1 << 0, 1 << 3);
    #pragma unroll
    for (int q = 0; q < NQ; ++q) {
        const int mask = 1 << (3 - q);
        apply_u3(sr, si, mask, w[q * 3 + 0], w[q * 3 + 1], w[q * 3 + 2]);
    }
    float z[NQ];
    #pragma unroll
    for (int q = 0; q < NQ; ++q) {
        const int mask = 1 << (3 - q);
        float acc = 0.f;
        #pragma unroll
        for (int i = 0; i < 16; ++i) {
            float pr = sr[i] * sr[i] + si[i] * si[i];
            acc += (i & mask) ? -pr : pr;
        }
        z[q] = acc;
    }
    float a = fcb[c];
    #pragma unroll
    for (int q = 0; q < NQ; ++q) a += z[q] * fcw[c * NQ + q];
    const float att = 1.0f / (1.0f + expf(-a));

    // stream my plane: L3-hot read * att -> NT store
    const f32x4* xp = reinterpret_cast<const f32x4*>(x) + (size_t)p * PLANE4;
    f32x4*       op = reinterpret_cast<f32x4*>(out)     + (size_t)p * PLANE4;
    const int t = threadIdx.x;
    #pragma unroll 4
    for (int i = 0; i < 64; ++i) {
        f32x4 v = xp[t + i * BS];
        __builtin_nontemporal_store(v * att, &op[t + i * BS]);
    }
}

extern "C" void kernel_launch(void* const* d_in, const int* in_sizes, int n_in,
                              void* d_out, int out_size, void* d_ws, size_t ws_size,
                              hipStream_t stream) {
    const float* x   = (const float*)d_in[0];
    const float* vw  = (const float*)d_in[1];
    const float* fcw = (const float*)d_in[2];
    const float* fcb = (const float*)d_in[3];
    float* out = (float*)d_out;

    float* part = (float*)d_ws;          // [3072], fully written each call

    mean_partial<<<NSEG, BS, 0, stream>>>(x, part);
    scale_vqc<<<NB, BS, 0, stream>>>(x, part, vw, fcw, fcb, out);
}